// Round 5
// baseline (235.007 us; speedup 1.0000x reference)
//
#include <hip/hip_runtime.h>
#include <hip/hip_bf16.h>
#include <stdint.h>

#define SCALE 0.25f

typedef __attribute__((ext_vector_type(8))) short bf16x8;
typedef __attribute__((ext_vector_type(4))) float f32x4;
typedef __attribute__((ext_vector_type(16))) float f32x16;

// ---------------------------------------------------------------- W repack
// W[o][i][t] (15 floats/row) -> W2[o][16] padded (b128-friendly)
__global__ __launch_bounds__(256) void prep_w2_kernel(const float* __restrict__ W,
                                                      float* __restrict__ W2) {
    int idx = blockIdx.x * 256 + threadIdx.x;   // 24576*16 threads
    int o = idx >> 4, j = idx & 15;
    W2[idx] = (j < 15) ? W[o * 15 + j] : 0.f;
}

// ---------------------------------------------------------------- fused, pipelined, ring-xo
// block = (bk, 32 s), 512 threads (8 waves). 16 stages (h,q):
//   { attn(h,q) -> xo ring || conv(next quarter) -> qkv[other] || (q==0: full-line
//     sweep(h-1) of 32 s rows) } + ONE barrier.
// xo ring [40][514]: writer rows (32h+8q+wid)%40, sweeper rows (32(h-1)+s)%40 --
// disjoint by construction. Full 128-B out lines per store instruction (8 lanes/line).
// conv reads x directly from global (3x aligned float4 per row; L1/L2-resident).
//
// LDS (dynamic, 162112 B):
//   qkv0 @0      : [8 s][3][512] bf16      24576
//   qkv1 @24576  :                         24576
//   xo   @49152  : [40][514] f32           82240
//   vT   @131392 : [8 w][16][40] ushort    10240
//   pT   @141632 : [8 w][32][40] ushort    20480
//   att  @0      : [512][36] f32 (overlay after main loop)  73728
#define LDS_TOTAL 162112

__global__ __launch_bounds__(512, 2) void fused3_kernel(const float* __restrict__ x,
                                                        const float* __restrict__ W2,
                                                        const float* __restrict__ bias,
                                                        float* __restrict__ out,
                                                        float* __restrict__ out_am) {
    extern __shared__ char smraw[];
    char* qkvbuf0 = smraw;
    char* qkvbuf1 = smraw + 24576;
    float* xo = (float*)(smraw + 49152);
    unsigned short* vT = (unsigned short*)(smraw + 131392);
    unsigned short* pT = (unsigned short*)(smraw + 141632);
    float* att = (float*)smraw;

    // XCD-aware decode: same-k_ blocks share 2 XCD slots -> W2 slice L2-resident
    int bi = blockIdx.x, slot = bi & 7, jj = bi >> 3;
    int k_ = slot >> 1, b = jj >> 4, st = ((slot & 1) << 4) | (jj & 15);
    int bk = b * 4 + k_;

    int t = threadIdx.x;
    int wid = t >> 6, lane = t & 63;
    int l31 = lane & 31, hi2 = lane >> 5;
    int l15 = lane & 15, hi4 = lane >> 4;

    int v = t >> 4, dk = t & 15;
    int g3 = (k_ * 32 + v) * 3;

    float w[3][16], bs[3];
    auto loadw = [&](int hh) {
        #pragma unroll
        for (int c3 = 0; c3 < 3; ++c3) {
            int row = (g3 + c3) * 64 + hh * 16 + dk;
            const float4* p = (const float4*)(W2 + (size_t)row * 16);
            float4 a0 = p[0], a1 = p[1], a2 = p[2], a3 = p[3];
            w[c3][0] = a0.x;  w[c3][1] = a0.y;  w[c3][2] = a0.z;  w[c3][3] = a0.w;
            w[c3][4] = a1.x;  w[c3][5] = a1.y;  w[c3][6] = a1.z;  w[c3][7] = a1.w;
            w[c3][8] = a2.x;  w[c3][9] = a2.y;  w[c3][10] = a2.z; w[c3][11] = a2.w;
            w[c3][12] = a3.x; w[c3][13] = a3.y; w[c3][14] = a3.z; w[c3][15] = a3.w;
            bs[c3] = bias[row];
        }
    };

    // conv for s-quarter qs -> dstraw; x read directly from global (aligned f4)
    auto conv_stage = [&](int qs, char* dstraw) {
        __hip_bfloat16* dst = (__hip_bfloat16*)dstraw;
        int idx0 = st * 32 + qs * 8 - 4;        // window [idx0, idx0+11]
        float xv[3][12];
        #pragma unroll
        for (int i = 0; i < 3; ++i) {
            const float* xr = x + ((size_t)b * 384 + k_ * 96 + v * 3 + i) * 1024;
            #pragma unroll
            for (int wq = 0; wq < 3; ++wq) {
                int s0 = idx0 + wq * 4;          // s0 % 4 == 0; s0<0 only st==0,qs==0,wq==0
                float4 f;
                if (s0 >= 0) f = *(const float4*)(xr + s0);
                else { f.x = 0.f; f.y = 0.f; f.z = 0.f; f.w = 0.f; }
                xv[i][wq * 4 + 0] = f.x; xv[i][wq * 4 + 1] = f.y;
                xv[i][wq * 4 + 2] = f.z; xv[i][wq * 4 + 3] = f.w;
            }
        }
        #pragma unroll
        for (int s8 = 0; s8 < 8; ++s8) {
            #pragma unroll
            for (int c3 = 0; c3 < 3; ++c3) {
                float a = bs[c3];
                #pragma unroll
                for (int i = 0; i < 3; ++i)
                    #pragma unroll
                    for (int tt = 0; tt < 5; ++tt)
                        a = fmaf(xv[i][s8 + tt], w[c3][i * 5 + tt], a);
                dst[(s8 * 3 + c3) * 512 + v * 16 + dk] = __float2bfloat16(a);
            }
        }
    };

    // full-line sweep of head hp: reads 32 ring rows, writes complete 128-B lines
    auto sweep = [&](int hp) {
        int rb = (32 * hp) % 40;
        int u = t >> 3;
        int s4 = (t & 7) * 4;
        #pragma unroll
        for (int j = 0; j < 8; ++j) {
            int c_loc = j * 64 + u;
            int col = c_loc ^ (4 * ((c_loc >> 4) & 7));
            float4 o;
            #pragma unroll
            for (int i2 = 0; i2 < 4; ++i2) {
                int r = rb + s4 + i2; if (r >= 40) r -= 40;
                (&o.x)[i2] = xo[r * 514 + col];
            }
            int qv = c_loc >> 4, dkc = c_loc & 15;
            int c = k_ * 2048 + qv * 64 + hp * 16 + dkc;
            *(float4*)(out + ((size_t)b * 8192 + c) * 1024 + st * 32 + s4) = o;
        }
    };

    float acc_am[4][16];
    #pragma unroll
    for (int a = 0; a < 4; ++a)
        #pragma unroll
        for (int r = 0; r < 16; ++r) acc_am[a][r] = 0.f;

    // ---- prologue
    loadw(0);
    conv_stage(0, qkvbuf0);
    __syncthreads();

    for (int h = 0; h < 4; ++h) {
        #pragma unroll
        for (int q = 0; q < 4; ++q) {
            if (q == 3 && h < 3) loadw(h + 1);

            // ---------------- attn(h,q): reads qkv[q&1], writes xo ring
            {
                char* qbuf = (q & 1) ? qkvbuf1 : qkvbuf0;
                const __hip_bfloat16* qb =
                    (const __hip_bfloat16*)qbuf + (wid * 3) * 512 + l31 * 16 + hi2 * 8;
                bf16x8 qf = *(const bf16x8*)qb;
                bf16x8 kf = *(const bf16x8*)(qb + 512);
                uint4 vv = *(const uint4*)(qb + 1024);

                {   // vT scatter [d][kv]
                    const unsigned short* us = (const unsigned short*)&vv;
                    #pragma unroll
                    for (int j = 0; j < 8; ++j)
                        vT[(wid * 16 + hi2 * 8 + j) * 40 + l31] = us[j];
                }

                f32x16 zc;
                #pragma unroll
                for (int i = 0; i < 16; ++i) zc[i] = 0.f;
                f32x16 lg = __builtin_amdgcn_mfma_f32_32x32x16_bf16(kf, qf, zc, 0, 0, 0);

                float p[16], m = -3.0e38f;
                #pragma unroll
                for (int r = 0; r < 16; ++r) { p[r] = lg[r] * SCALE; m = fmaxf(m, p[r]); }
                m = fmaxf(m, __shfl_xor(m, 32));
                float ssum = 0.f;
                #pragma unroll
                for (int r = 0; r < 16; ++r) { p[r] = __expf(p[r] - m); ssum += p[r]; }
                ssum += __shfl_xor(ssum, 32);
                float inv = 1.f / ssum;
                #pragma unroll
                for (int r = 0; r < 16; ++r) { p[r] *= inv; acc_am[q][r] += p[r]; }

                // pT [qv][kv] bf16, write-swizzled
                unsigned* pTrow = (unsigned*)(pT + (size_t)(wid * 32 + l31) * 40);
                int wsw = (l31 >> 3) & 1 ? 4 : 0;
                #pragma unroll
                for (int mm = 0; mm < 8; ++mm) {
                    unsigned pk;
                    asm("v_cvt_pk_bf16_f32 %0, %1, %2"
                        : "=v"(pk) : "v"(p[2 * mm]), "v"(p[2 * mm + 1]));
                    pTrow[((mm & 1) + 4 * (mm >> 1) + 2 * hi2) ^ wsw] = pk;
                }

                int rsw = (l15 >> 3) & 1 ? 8 : 0;   // ushort-offset XOR (== dword ^4)
                bf16x8 vf = *(const bf16x8*)&vT[(wid * 16 + l15) * 40 + hi4 * 8];
                bf16x8 p1 = *(const bf16x8*)&pT[(wid * 32 + l15) * 40 + (hi4 * 8 ^ rsw)];
                bf16x8 p2 = *(const bf16x8*)&pT[(wid * 32 + 16 + l15) * 40 + (hi4 * 8 ^ rsw)];
                f32x4 z4;
                #pragma unroll
                for (int i = 0; i < 4; ++i) z4[i] = 0.f;
                f32x4 xo1 = __builtin_amdgcn_mfma_f32_16x16x32_bf16(vf, p1, z4, 0, 0, 0);
                f32x4 xo2 = __builtin_amdgcn_mfma_f32_16x16x32_bf16(vf, p2, z4, 0, 0, 0);

                // ring row (32h + 8q + wid) % 40; col (qv*16+d) ^ 4*(qv&7)
                int rr = (32 * h + 8 * q + wid) % 40;
                float* row = xo + rr * 514;
                int sw = 4 * (l15 & 7);
                *(f32x4*)(row + ((l15 * 16 + hi4 * 4) ^ sw)) = xo1;
                *(f32x4*)(row + (((16 + l15) * 16 + hi4 * 4) ^ sw)) = xo2;
            }

            // ---------------- conv(next stage's quarter) -> qkv[(q+1)&1]
            if (!(h == 3 && q == 3)) {
                conv_stage((q + 1) & 3, ((q + 1) & 1) ? qkvbuf1 : qkvbuf0);
            }

            // ---------------- full-line sweep of previous head
            if (q == 0 && h > 0) sweep(h - 1);

            __syncthreads();
        }
    }
    // epilogue: sweep last head, then attn-mean
    sweep(3);
    __syncthreads();

    // ---------------- attn-mean: att[512][36] overlay, 2 passes over qv halves
    #pragma unroll
    for (int pass = 0; pass < 2; ++pass) {
        if (pass) __syncthreads();
        if ((l31 >> 4) == pass) {
            int qh = l31 & 15;
            int csw = 4 * (qh & 7);
            #pragma unroll
            for (int q = 0; q < 4; ++q) {
                int sp = q * 8 + wid;
                int colp = sp ^ csw;
                #pragma unroll
                for (int r = 0; r < 16; ++r) {
                    int kv = (r & 3) + 8 * (r >> 2) + 4 * hi2;
                    att[(qh * 32 + kv) * 36 + colp] = 0.25f * acc_am[q][r];
                }
            }
        }
        __syncthreads();
        #pragma unroll
        for (int j = 0; j < 8; ++j) {
            int tr = j * 64 + (t >> 3);
            int csw = 4 * ((tr >> 5) & 7);
            int s4 = (t & 7) * 4;
            float4 o;
            o.x = att[tr * 36 + ((s4 + 0) ^ csw)];
            o.y = att[tr * 36 + ((s4 + 1) ^ csw)];
            o.z = att[tr * 36 + ((s4 + 2) ^ csw)];
            o.w = att[tr * 36 + ((s4 + 3) ^ csw)];
            *(float4*)(out_am + ((size_t)bk * 1024 + pass * 512 + tr) * 1024 + st * 32 + s4) = o;
        }
    }
}

// ---------------------------------------------------------------- launch
extern "C" void kernel_launch(void* const* d_in, const int* in_sizes, int n_in,
                              void* d_out, int out_size, void* d_ws, size_t ws_size,
                              hipStream_t stream) {
    const float* x = (const float*)d_in[0];
    const float* W = (const float*)d_in[1];
    const float* bias = (const float*)d_in[2];
    float* out = (float*)d_out;
    float* out_am = out + (size_t)33554432;   // xo is 4*8192*1024

    float* W2 = (float*)d_ws;                 // 24576*16*4 = 1.5 MB

    (void)hipFuncSetAttribute((const void*)fused3_kernel,
                              hipFuncAttributeMaxDynamicSharedMemorySize, LDS_TOTAL);

    prep_w2_kernel<<<1536, 256, 0, stream>>>(W, W2);
    fused3_kernel<<<512, 512, LDS_TOTAL, stream>>>(x, W2, bias, out, out_am);
}

// Round 6
// 142.361 us; speedup vs baseline: 1.6508x; 1.6508x over previous
//
#include <hip/hip_runtime.h>
#include <hip/hip_bf16.h>
#include <stdint.h>

#define SCALE 0.25f

typedef __attribute__((ext_vector_type(8))) short bf16x8;
typedef __attribute__((ext_vector_type(4))) float f32x4;
typedef __attribute__((ext_vector_type(16))) float f32x16;

// ---------------------------------------------------------------- W repack
// W[o][i][t] (15 floats/row) -> W2[o][16] padded (b128-friendly)
__global__ __launch_bounds__(256) void prep_w2_kernel(const float* __restrict__ W,
                                                      float* __restrict__ W2) {
    int idx = blockIdx.x * 256 + threadIdx.x;   // 24576*16 threads
    int o = idx >> 4, j = idx & 15;
    W2[idx] = (j < 15) ? W[o * 15 + j] : 0.f;
}

// ---------------------------------------------------------------- fused, pipelined, ring-xo
// block = (bk, 32 s), 512 threads (8 waves). 16 stages (h,q):
//   { attn(h,q) -> xo ring || conv(next quarter) -> qk/vTd[other] || (q==0:
//     full-line sweep(h-1) of 32 s rows) } + ONE barrier.
// xs staged in LDS as f16 (loaded once). conv writes V directly TRANSPOSED
// (vTd[s][dk][v]) so attn needs no v-scatter. xo ring [40][514] f32: writer
// rows (32h+8q+wid)%40, sweeper rows (32(h-1)+s)%40 -- disjoint. Sweeps emit
// complete 128-B lines (8 lanes/line).
//
// LDS (dynamic, 162880 B):
//   xs  @0      : [96][36] f16              6912
//   qk0 @6912   : [8 s][2][512] bf16       16384
//   qk1 @23296  :                          16384
//   vT0 @39680  : [8 s][16 dk][40 v] bf16  10240
//   vT1 @49920  :                          10240
//   pT  @60160  : [8 w][32 qv][40] ushort  20480
//   ring@80640  : [40][514] f32            82240
//   att @0      : [512][36] f32 overlay after main loop (73728, clobbers xs..pT)
#define XS_OFF 0
#define QK0_OFF 6912
#define QK1_OFF 23296
#define VT0_OFF 39680
#define VT1_OFF 49920
#define PT_OFF 60160
#define RING_OFF 80640
#define LDS_TOTAL 162880

__global__ __launch_bounds__(512) void fused4_kernel(const float* __restrict__ x,
                                                     const float* __restrict__ W2,
                                                     const float* __restrict__ bias,
                                                     float* __restrict__ out,
                                                     float* __restrict__ out_am) {
    extern __shared__ char smraw[];
    _Float16* xs = (_Float16*)(smraw + XS_OFF);
    unsigned short* pT = (unsigned short*)(smraw + PT_OFF);
    float* xo = (float*)(smraw + RING_OFF);
    float* att = (float*)smraw;

    // XCD-aware decode: same-k_ blocks share 2 XCD slots -> W2 slice L2-resident
    int bi = blockIdx.x, slot = bi & 7, jj = bi >> 3;
    int k_ = slot >> 1, b = jj >> 4, st = ((slot & 1) << 4) | (jj & 15);
    int bk = b * 4 + k_;

    int t = threadIdx.x;
    int wid = t >> 6, lane = t & 63;
    int l31 = lane & 31, hi2 = lane >> 5;
    int l15 = lane & 15, hi4 = lane >> 4;

    int v = t >> 4, dk = t & 15;
    int g3 = (k_ * 32 + v) * 3;

    float w[3][16], bs[3];
    auto loadw = [&](int hh) {
        #pragma unroll
        for (int c3 = 0; c3 < 3; ++c3) {
            int row = (g3 + c3) * 64 + hh * 16 + dk;
            const float4* p = (const float4*)(W2 + (size_t)row * 16);
            float4 a0 = p[0], a1 = p[1], a2 = p[2], a3 = p[3];
            w[c3][0] = a0.x;  w[c3][1] = a0.y;  w[c3][2] = a0.z;  w[c3][3] = a0.w;
            w[c3][4] = a1.x;  w[c3][5] = a1.y;  w[c3][6] = a1.z;  w[c3][7] = a1.w;
            w[c3][8] = a2.x;  w[c3][9] = a2.y;  w[c3][10] = a2.z; w[c3][11] = a2.w;
            w[c3][12] = a3.x; w[c3][13] = a3.y; w[c3][14] = a3.z; w[c3][15] = a3.w;
            bs[c3] = bias[row];
        }
    };

    // conv for s-quarter qs -> qk[bufi] (q,k) and vTd[bufi] (v, transposed)
    auto conv_stage = [&](int qs, int bufi) {
        __hip_bfloat16* qk = (__hip_bfloat16*)(smraw + (bufi ? QK1_OFF : QK0_OFF));
        __hip_bfloat16* vt = (__hip_bfloat16*)(smraw + (bufi ? VT1_OFF : VT0_OFF));
        float xw[3][12];
        #pragma unroll
        for (int i = 0; i < 3; ++i)
            #pragma unroll
            for (int j = 0; j < 12; ++j)
                xw[i][j] = (float)xs[(v * 3 + i) * 36 + qs * 8 + j];
        #pragma unroll
        for (int s8 = 0; s8 < 8; ++s8) {
            float a0 = bs[0], a1 = bs[1], a2 = bs[2];
            #pragma unroll
            for (int i = 0; i < 3; ++i)
                #pragma unroll
                for (int tt = 0; tt < 5; ++tt) {
                    float xv = xw[i][s8 + tt];
                    a0 = fmaf(xv, w[0][i * 5 + tt], a0);
                    a1 = fmaf(xv, w[1][i * 5 + tt], a1);
                    a2 = fmaf(xv, w[2][i * 5 + tt], a2);
                }
            qk[(s8 * 2 + 0) * 512 + v * 16 + dk] = __float2bfloat16(a0);
            qk[(s8 * 2 + 1) * 512 + v * 16 + dk] = __float2bfloat16(a1);
            vt[(s8 * 16 + dk) * 40 + v] = __float2bfloat16(a2);
        }
    };

    // full-line sweep of head hp: reads 32 ring rows, writes complete 128-B lines
    auto sweep = [&](int hp) {
        int rb = (32 * hp) % 40;
        int u = t >> 3;
        int s4 = (t & 7) * 4;
        #pragma unroll
        for (int j = 0; j < 8; ++j) {
            int c_loc = j * 64 + u;
            int col = c_loc ^ (4 * ((c_loc >> 4) & 7));
            float4 o;
            #pragma unroll
            for (int i2 = 0; i2 < 4; ++i2) {
                int r = rb + s4 + i2; if (r >= 40) r -= 40;
                (&o.x)[i2] = xo[r * 514 + col];
            }
            int qv = c_loc >> 4, dkc = c_loc & 15;
            int c = k_ * 2048 + qv * 64 + hp * 16 + dkc;
            *(float4*)(out + ((size_t)b * 8192 + c) * 1024 + st * 32 + s4) = o;
        }
    };

    float acc_am[4][16];
    #pragma unroll
    for (int a = 0; a < 4; ++a)
        #pragma unroll
        for (int r = 0; r < 16; ++r) acc_am[a][r] = 0.f;

    // ---- x window [96 ch][36 s] -> LDS f16 (once per block)
    loadw(0);
    {
        int sbase = st * 32 - 4;
        #pragma unroll
        for (int i = 0; i < 7; ++i) {
            int idx = i * 512 + t;
            if (idx < 3456) {
                int row = idx / 36, col = idx - row * 36;
                int sg = sbase + col;
                float val = (sg >= 0) ? x[((size_t)b * 384 + k_ * 96 + row) * 1024 + sg] : 0.f;
                xs[idx] = (_Float16)val;
            }
        }
    }
    __syncthreads();
    conv_stage(0, 0);
    __syncthreads();

    for (int h = 0; h < 4; ++h) {
        #pragma unroll
        for (int q = 0; q < 4; ++q) {
            if (q == 3 && h < 3) loadw(h + 1);

            // ---------------- attn(h,q): reads qk/vTd[q&1], writes xo ring
            {
                const __hip_bfloat16* qk =
                    (const __hip_bfloat16*)(smraw + ((q & 1) ? QK1_OFF : QK0_OFF));
                const __hip_bfloat16* vt =
                    (const __hip_bfloat16*)(smraw + ((q & 1) ? VT1_OFF : VT0_OFF));
                const __hip_bfloat16* qb = qk + (wid * 2) * 512 + l31 * 16 + hi2 * 8;
                bf16x8 qf = *(const bf16x8*)qb;
                bf16x8 kf = *(const bf16x8*)(qb + 512);

                f32x16 zc;
                #pragma unroll
                for (int i = 0; i < 16; ++i) zc[i] = 0.f;
                f32x16 lg = __builtin_amdgcn_mfma_f32_32x32x16_bf16(kf, qf, zc, 0, 0, 0);

                float p[16], m = -3.0e38f;
                #pragma unroll
                for (int r = 0; r < 16; ++r) { p[r] = lg[r] * SCALE; m = fmaxf(m, p[r]); }
                m = fmaxf(m, __shfl_xor(m, 32));
                float ssum = 0.f;
                #pragma unroll
                for (int r = 0; r < 16; ++r) { p[r] = __expf(p[r] - m); ssum += p[r]; }
                ssum += __shfl_xor(ssum, 32);
                float inv = 1.f / ssum;
                #pragma unroll
                for (int r = 0; r < 16; ++r) { p[r] *= inv; acc_am[q][r] += p[r]; }

                // pT [qv][kv] bf16, write-swizzled
                unsigned* pTrow = (unsigned*)(pT + (size_t)(wid * 32 + l31) * 40);
                int wsw = (l31 >> 3) & 1 ? 4 : 0;
                #pragma unroll
                for (int mm = 0; mm < 8; ++mm) {
                    unsigned pk;
                    asm("v_cvt_pk_bf16_f32 %0, %1, %2"
                        : "=v"(pk) : "v"(p[2 * mm]), "v"(p[2 * mm + 1]));
                    pTrow[((mm & 1) + 4 * (mm >> 1) + 2 * hi2) ^ wsw] = pk;
                }

                int rsw = (l15 >> 3) & 1 ? 8 : 0;   // ushort-offset XOR (== dword ^4)
                bf16x8 vf = *(const bf16x8*)&vt[(wid * 16 + l15) * 40 + hi4 * 8];
                bf16x8 p1 = *(const bf16x8*)&pT[(wid * 32 + l15) * 40 + (hi4 * 8 ^ rsw)];
                bf16x8 p2 = *(const bf16x8*)&pT[(wid * 32 + 16 + l15) * 40 + (hi4 * 8 ^ rsw)];
                f32x4 z4;
                #pragma unroll
                for (int i = 0; i < 4; ++i) z4[i] = 0.f;
                f32x4 xo1 = __builtin_amdgcn_mfma_f32_16x16x32_bf16(vf, p1, z4, 0, 0, 0);
                f32x4 xo2 = __builtin_amdgcn_mfma_f32_16x16x32_bf16(vf, p2, z4, 0, 0, 0);

                // ring row (32h + 8q + wid) % 40; col (qv*16+d) ^ 4*(qv&7)
                int rr = (32 * h + 8 * q + wid) % 40;
                float* row = xo + rr * 514;
                int sw = 4 * (l15 & 7);
                *(f32x4*)(row + ((l15 * 16 + hi4 * 4) ^ sw)) = xo1;
                *(f32x4*)(row + (((16 + l15) * 16 + hi4 * 4) ^ sw)) = xo2;
            }

            // ---------------- conv(next stage's quarter) -> qk/vTd[(q+1)&1]
            if (!(h == 3 && q == 3)) {
                conv_stage((q + 1) & 3, (q + 1) & 1);
            }

            // ---------------- full-line sweep of previous head
            if (q == 0 && h > 0) sweep(h - 1);

            __syncthreads();
        }
    }
    // epilogue: sweep last head, then attn-mean
    sweep(3);
    __syncthreads();

    // ---------------- attn-mean: att[512][36] overlay, 2 passes over qv halves
    #pragma unroll
    for (int pass = 0; pass < 2; ++pass) {
        if (pass) __syncthreads();
        if ((l31 >> 4) == pass) {
            int qh = l31 & 15;
            int csw = 4 * (qh & 7);
            #pragma unroll
            for (int q = 0; q < 4; ++q) {
                int sp = q * 8 + wid;
                int colp = sp ^ csw;
                #pragma unroll
                for (int r = 0; r < 16; ++r) {
                    int kv = (r & 3) + 8 * (r >> 2) + 4 * hi2;
                    att[(qh * 32 + kv) * 36 + colp] = 0.25f * acc_am[q][r];
                }
            }
        }
        __syncthreads();
        #pragma unroll
        for (int j = 0; j < 8; ++j) {
            int tr = j * 64 + (t >> 3);
            int csw = 4 * ((tr >> 5) & 7);
            int s4 = (t & 7) * 4;
            float4 o;
            o.x = att[tr * 36 + ((s4 + 0) ^ csw)];
            o.y = att[tr * 36 + ((s4 + 1) ^ csw)];
            o.z = att[tr * 36 + ((s4 + 2) ^ csw)];
            o.w = att[tr * 36 + ((s4 + 3) ^ csw)];
            *(float4*)(out_am + ((size_t)bk * 1024 + pass * 512 + tr) * 1024 + st * 32 + s4) = o;
        }
    }
}

// ---------------------------------------------------------------- launch
extern "C" void kernel_launch(void* const* d_in, const int* in_sizes, int n_in,
                              void* d_out, int out_size, void* d_ws, size_t ws_size,
                              hipStream_t stream) {
    const float* x = (const float*)d_in[0];
    const float* W = (const float*)d_in[1];
    const float* bias = (const float*)d_in[2];
    float* out = (float*)d_out;
    float* out_am = out + (size_t)33554432;   // xo is 4*8192*1024

    float* W2 = (float*)d_ws;                 // 24576*16*4 = 1.5 MB

    (void)hipFuncSetAttribute((const void*)fused4_kernel,
                              hipFuncAttributeMaxDynamicSharedMemorySize, LDS_TOTAL);

    prep_w2_kernel<<<1536, 256, 0, stream>>>(W, W2);
    fused4_kernel<<<512, 512, LDS_TOTAL, stream>>>(x, W2, bias, out, out_am);
}